// Round 1
// baseline (2121.749 us; speedup 1.0000x reference)
//
#include <hip/hip_runtime.h>
#include <math.h>

#define NNODES 100000
#define NEDGES 800000
#define DIN    256
#define HID    64
#define NC     40
#define NL     2
#define EPSL   1e-5f
#define CHUNK  1024
#define NCHUNK ((NNODES + CHUNK - 1) / CHUNK)   // 98

__device__ __forceinline__ float wave_allsum(float v) {
#pragma unroll
  for (int off = 32; off > 0; off >>= 1) v += __shfl_xor(v, off);
  return v;
}

// ---------------- CSR build ----------------
__global__ void k_hist(const int* __restrict__ ei, int* __restrict__ deg) {
  for (int e = blockIdx.x * blockDim.x + threadIdx.x; e < NEDGES;
       e += gridDim.x * blockDim.x)
    atomicAdd(&deg[ei[NEDGES + e]], 1);
}

__global__ void k_scan1(const int* __restrict__ deg, int* __restrict__ csum) {
  __shared__ int sdata[256];
  int base = blockIdx.x * CHUNK;
  int s = 0;
  for (int t = threadIdx.x; t < CHUNK; t += 256) {
    int idx = base + t;
    if (idx < NNODES) s += deg[idx];
  }
  sdata[threadIdx.x] = s;
  __syncthreads();
  for (int off = 128; off > 0; off >>= 1) {
    if (threadIdx.x < off) sdata[threadIdx.x] += sdata[threadIdx.x + off];
    __syncthreads();
  }
  if (threadIdx.x == 0) csum[blockIdx.x] = sdata[0];
}

__global__ void k_scan2(const int* __restrict__ csum, int* __restrict__ cpref) {
  if (threadIdx.x == 0 && blockIdx.x == 0) {
    int run = 0;
    for (int i = 0; i < NCHUNK; ++i) { cpref[i] = run; run += csum[i]; }
  }
}

__global__ void k_scan3(const int* __restrict__ deg, const int* __restrict__ cpref,
                        int* __restrict__ offs) {
  __shared__ int bufA[CHUNK], bufB[CHUNK];
  int base = blockIdx.x * CHUNK;
  int orig[4];
#pragma unroll
  for (int i = 0; i < 4; ++i) {
    int t = threadIdx.x + i * 256;
    int idx = base + t;
    orig[i] = (idx < NNODES) ? deg[idx] : 0;
    bufA[t] = orig[i];
  }
  __syncthreads();
  int* src = bufA; int* dst = bufB;
  for (int off = 1; off < CHUNK; off <<= 1) {
#pragma unroll
    for (int i = 0; i < 4; ++i) {
      int t = threadIdx.x + i * 256;
      int vv = src[t];
      if (t >= off) vv += src[t - off];
      dst[t] = vv;
    }
    __syncthreads();
    int* tmp = src; src = dst; dst = tmp;
  }
  int cp = cpref[blockIdx.x];
#pragma unroll
  for (int i = 0; i < 4; ++i) {
    int t = threadIdx.x + i * 256;
    int idx = base + t;
    if (idx < NNODES) {
      offs[idx] = cp + src[t] - orig[i];
      if (idx == NNODES - 1) offs[NNODES] = cp + src[t];
    }
  }
}

__global__ void k_fill(const int* __restrict__ ei, const int* __restrict__ deg,
                       const int* __restrict__ offs, int* __restrict__ cursor,
                       int* __restrict__ ebuf, float* __restrict__ wbuf) {
  for (int e = blockIdx.x * blockDim.x + threadIdx.x; e < NEDGES;
       e += gridDim.x * blockDim.x) {
    int r = ei[e], c = ei[NEDGES + e];
    int pos = offs[c] + atomicAdd(&cursor[c], 1);
    ebuf[pos] = r;
    int dc = deg[c], dr = deg[r];
    wbuf[pos] = (dr > 0)
        ? sqrtf(1.0f / (float)dc) * sqrtf(1.0f / (float)dr) : 0.0f;
  }
}

// ---------------- fc0 + LN + relu ----------------
__global__ __launch_bounds__(256) void k_fc0(
    const float* __restrict__ x, const float* __restrict__ w,
    const float* __restrict__ b, const float* __restrict__ lnw_,
    const float* __restrict__ lnb_, float* __restrict__ h) {
  __shared__ float Wl[DIN * HID];   // 64 KB
  for (int t = threadIdx.x; t < DIN * HID; t += 256) Wl[t] = w[t];
  __syncthreads();
  const int wave = threadIdx.x >> 6, lane = threadIdx.x & 63;
  const float bias = b[lane], lw = lnw_[lane], lb = lnb_[lane];
  for (int row = blockIdx.x * 4 + wave; row < NNODES; row += gridDim.x * 4) {
    const float4 xv = *(const float4*)(x + (size_t)row * DIN + lane * 4);
    float acc = bias;
#pragma unroll
    for (int g = 0; g < 64; ++g) {
      float x0 = __shfl(xv.x, g), x1 = __shfl(xv.y, g);
      float x2 = __shfl(xv.z, g), x3 = __shfl(xv.w, g);
      const float* wp = &Wl[g * 4 * HID + lane];
      acc = fmaf(x0, wp[0], acc);
      acc = fmaf(x1, wp[HID], acc);
      acc = fmaf(x2, wp[2 * HID], acc);
      acc = fmaf(x3, wp[3 * HID], acc);
    }
    float mu = wave_allsum(acc) * (1.0f / 64.0f);
    float d = acc - mu;
    float var = wave_allsum(d * d) * (1.0f / 64.0f);
    float hv = d * (1.0f / sqrtf(var + EPSL)) * lw + lb;
    h[(size_t)row * HID + lane] = fmaxf(hv, 0.0f);
  }
}

// ---------------- QKV GEMM + global reductions ----------------
// block = 192 threads: wave0 -> q, wave1 -> k, wave2 -> v; each thread owns
// 2 output cols with W in registers; h row broadcast via shfl.
__global__ __launch_bounds__(192) void k_qkv(
    const float* __restrict__ h,
    const float* __restrict__ Wq, const float* __restrict__ Wk,
    const float* __restrict__ Wv,
    const float* __restrict__ bq, const float* __restrict__ bk,
    const float* __restrict__ bv,
    float* __restrict__ q, float* __restrict__ k, float* __restrict__ v,
    float* __restrict__ red) {
  const int tid = threadIdx.x;
  const int wave = tid >> 6;   // 0:q 1:k 2:v
  const int lane = tid & 63;
  const int j0 = lane * 2;
  const float* W = (wave == 0) ? Wq : (wave == 1) ? Wk : Wv;
  const float* B = (wave == 0) ? bq : (wave == 1) ? bk : bv;
  float* outp    = (wave == 0) ? q  : (wave == 1) ? k  : v;
  float w0[64], w1[64];
#pragma unroll
  for (int kk = 0; kk < 64; ++kk) {
    float2 wv_ = *(const float2*)(W + kk * 128 + j0);
    w0[kk] = wv_.x; w1[kk] = wv_.y;
  }
  const float b0 = B[j0], b1 = B[j0 + 1];
  float s_sq = 0.f, sum0 = 0.f, sum1 = 0.f;
  for (int row = blockIdx.x; row < NNODES; row += gridDim.x) {
    float hv = h[(size_t)row * HID + lane];
    float a0 = 0.f, a1 = 0.f;
#pragma unroll
    for (int kk = 0; kk < 64; ++kk) {
      float hk = __shfl(hv, kk);
      a0 = fmaf(hk, w0[kk], a0);
      a1 = fmaf(hk, w1[kk], a1);
    }
    a0 += b0; a1 += b1;
    *(float2*)(outp + (size_t)row * 128 + j0) = make_float2(a0, a1);
    s_sq += a0 * a0 + a1 * a1;
    sum0 += a0; sum1 += a1;
  }
  if (wave == 0) {
    float t = wave_allsum(s_sq);
    if (lane == 0) atomicAdd(&red[0], t);
  } else if (wave == 1) {
    float t = wave_allsum(s_sq);
    if (lane == 0) atomicAdd(&red[1], t);
    atomicAdd(&red[2 + j0], sum0);
    atomicAdd(&red[2 + j0 + 1], sum1);
  } else {
    atomicAdd(&red[130 + j0], sum0);
    atomicAdd(&red[130 + j0 + 1], sum1);
  }
}

// ---------------- KVS = sum_n k[n,h,:] (outer) v[n,h,:] ----------------
__global__ __launch_bounds__(256) void k_kvs(
    const float* __restrict__ k, const float* __restrict__ v,
    float* __restrict__ red) {
  __shared__ float kc[64 * 128], vc[64 * 128];   // 64 KB
  const int tid = threadIdx.x;
  const int hh = tid >> 7, rem = tid & 127;
  const int mm = rem >> 1, db = (rem & 1) * 32;
  float acc[32];
#pragma unroll
  for (int i = 0; i < 32; ++i) acc[i] = 0.f;
  const float4* k4 = (const float4*)k;
  const float4* v4 = (const float4*)v;
  for (int base = blockIdx.x * 64; base < NNODES; base += gridDim.x * 64) {
    for (int t = tid; t < 64 * 32; t += 256) {
      int node = base + (t >> 5);
      int c4 = t & 31;
      float4 kk4 = make_float4(0.f, 0.f, 0.f, 0.f), vv4 = kk4;
      if (node < NNODES) {
        kk4 = k4[(size_t)node * 32 + c4];
        vv4 = v4[(size_t)node * 32 + c4];
      }
      *(float4*)&kc[t * 4] = kk4;
      *(float4*)&vc[t * 4] = vv4;
    }
    __syncthreads();
    for (int nn = 0; nn < 64; ++nn) {
      float kvv = kc[nn * 128 + hh * 64 + mm];
      const float4* vp = (const float4*)&vc[nn * 128 + hh * 64 + db];
#pragma unroll
      for (int dq = 0; dq < 8; ++dq) {
        float4 vv = vp[dq];
        acc[4 * dq + 0] = fmaf(kvv, vv.x, acc[4 * dq + 0]);
        acc[4 * dq + 1] = fmaf(kvv, vv.y, acc[4 * dq + 1]);
        acc[4 * dq + 2] = fmaf(kvv, vv.z, acc[4 * dq + 2]);
        acc[4 * dq + 3] = fmaf(kvv, vv.w, acc[4 * dq + 3]);
      }
    }
    __syncthreads();
  }
  float* kvs_out = red + 258 + hh * 4096 + mm * 64 + db;
#pragma unroll
  for (int dd = 0; dd < 32; ++dd) atomicAdd(&kvs_out[dd], acc[dd]);
}

// ---------------- attn + gcn + head-mean + residual + LN ----------------
__global__ __launch_bounds__(256) void k_combine(
    const float* __restrict__ q, const float* __restrict__ v,
    const float* __restrict__ prev, const int* __restrict__ offs,
    const int* __restrict__ ebuf, const float* __restrict__ wbuf,
    const float* __restrict__ red, const float* __restrict__ lnw_,
    const float* __restrict__ lnb_, float* __restrict__ hout) {
  __shared__ float kvsl[8192];   // 32 KB
  __shared__ float ksl[128], vsl[128];
  for (int t = threadIdx.x; t < 8192; t += 256) kvsl[t] = red[258 + t];
  if (threadIdx.x < 128) {
    ksl[threadIdx.x] = red[2 + threadIdx.x];
    vsl[threadIdx.x] = red[130 + threadIdx.x];
  }
  __syncthreads();
  const float inv_qk = (1.0f / sqrtf(red[0])) * (1.0f / sqrtf(red[1]));
  const int wave = threadIdx.x >> 6, lane = threadIdx.x & 63;
  const float lw = lnw_[lane], lb = lnb_[lane];
  for (int node = blockIdx.x * 4 + wave; node < NNODES; node += gridDim.x * 4) {
    float q0 = q[(size_t)node * 128 + lane];
    float q1 = q[(size_t)node * 128 + 64 + lane];
    float a0 = 0.f, a1 = 0.f, d0 = 0.f, d1 = 0.f;
#pragma unroll 8
    for (int m = 0; m < 64; ++m) {
      float qm0 = __shfl(q0, m), qm1 = __shfl(q1, m);
      a0 = fmaf(qm0, kvsl[m * 64 + lane], a0);
      d0 = fmaf(qm0, ksl[m], d0);
      a1 = fmaf(qm1, kvsl[4096 + m * 64 + lane], a1);
      d1 = fmaf(qm1, ksl[64 + m], d1);
    }
    float attn0 = (a0 * inv_qk + vsl[lane])      / (d0 * inv_qk + (float)NNODES);
    float attn1 = (a1 * inv_qk + vsl[64 + lane]) / (d1 * inv_qk + (float)NNODES);
    float g0 = 0.f, g1 = 0.f;
    int s = offs[node], e = offs[node + 1];
    for (int idx = s; idx < e; ++idx) {
      int src = ebuf[idx];
      float wv_ = wbuf[idx];
      g0 = fmaf(wv_, v[(size_t)src * 128 + lane], g0);
      g1 = fmaf(wv_, v[(size_t)src * 128 + 64 + lane], g1);
    }
    float om = ((attn0 + g0) + (attn1 + g1)) * 0.5f;
    float pre = 0.5f * om + 0.5f * prev[(size_t)node * 64 + lane];
    float mu = wave_allsum(pre) * (1.0f / 64.0f);
    float d = pre - mu;
    float var = wave_allsum(d * d) * (1.0f / 64.0f);
    hout[(size_t)node * 64 + lane] = d * (1.0f / sqrtf(var + EPSL)) * lw + lb;
  }
}

// ---------------- final classifier ----------------
__global__ __launch_bounds__(256) void k_final(
    const float* __restrict__ h, const float* __restrict__ w,
    const float* __restrict__ b, float* __restrict__ out) {
  __shared__ float Wl[HID * NC];
  for (int t = threadIdx.x; t < HID * NC; t += 256) Wl[t] = w[t];
  __syncthreads();
  const int wave = threadIdx.x >> 6, lane = threadIdx.x & 63;
  const int col = lane < NC ? lane : 0;
  const float bias = b[col];
  for (int row = blockIdx.x * 4 + wave; row < NNODES; row += gridDim.x * 4) {
    float hv = h[(size_t)row * HID + lane];
    float acc = bias;
#pragma unroll
    for (int kk = 0; kk < 64; ++kk) {
      float hk = __shfl(hv, kk);
      acc = fmaf(hk, Wl[kk * NC + col], acc);
    }
    if (lane < NC) out[(size_t)row * NC + lane] = acc;
  }
}

extern "C" void kernel_launch(void* const* d_in, const int* in_sizes, int n_in,
                              void* d_out, int out_size, void* d_ws,
                              size_t ws_size, hipStream_t stream) {
  const float* x     = (const float*)d_in[0];
  const int*   ei    = (const int*)d_in[1];
  const float* fc0_w = (const float*)d_in[2];
  const float* fc0_b = (const float*)d_in[3];
  const float* ln_w  = (const float*)d_in[4];
  const float* ln_b  = (const float*)d_in[5];
  const float* Wq    = (const float*)d_in[6];
  const float* Wk    = (const float*)d_in[7];
  const float* Wv    = (const float*)d_in[8];
  const float* bq    = (const float*)d_in[9];
  const float* bk    = (const float*)d_in[10];
  const float* bv    = (const float*)d_in[11];
  const float* fco_w = (const float*)d_in[12];
  const float* fco_b = (const float*)d_in[13];
  float* out = (float*)d_out;

  char* p = (char*)d_ws;
  auto alloc = [&](size_t bytes) {
    char* r = p;
    p += (bytes + 255) & ~(size_t)255;
    return r;
  };
  float* q    = (float*)alloc(sizeof(float) * (size_t)NNODES * 128);
  float* kbuf = (float*)alloc(sizeof(float) * (size_t)NNODES * 128);
  float* vbuf = (float*)alloc(sizeof(float) * (size_t)NNODES * 128);
  float* hA   = (float*)alloc(sizeof(float) * (size_t)NNODES * HID);
  float* hB   = (float*)alloc(sizeof(float) * (size_t)NNODES * HID);
  float* red  = (float*)alloc(sizeof(float) * 8704);
  int* deg    = (int*)alloc(sizeof(int) * NNODES);
  int* offs   = (int*)alloc(sizeof(int) * (NNODES + 1));
  int* cursor = (int*)alloc(sizeof(int) * NNODES);
  int* ebuf   = (int*)alloc(sizeof(int) * NEDGES);
  float* wbuf = (float*)alloc(sizeof(float) * NEDGES);
  int* csum   = (int*)alloc(sizeof(int) * 128);
  int* cpref  = (int*)alloc(sizeof(int) * 128);

  // ---- CSR build (once per call; edge_index fixed within a call) ----
  hipMemsetAsync(deg, 0, sizeof(int) * NNODES, stream);
  hipMemsetAsync(cursor, 0, sizeof(int) * NNODES, stream);
  k_hist<<<1024, 256, 0, stream>>>(ei, deg);
  k_scan1<<<NCHUNK, 256, 0, stream>>>(deg, csum);
  k_scan2<<<1, 64, 0, stream>>>(csum, cpref);
  k_scan3<<<NCHUNK, 256, 0, stream>>>(deg, cpref, offs);
  k_fill<<<1024, 256, 0, stream>>>(ei, deg, offs, cursor, ebuf, wbuf);

  // ---- input projection ----
  k_fc0<<<512, 256, 0, stream>>>(x, fc0_w, fc0_b, ln_w, ln_b, hA);

  float* hin = hA;
  float* hot = hB;
  for (int l = 0; l < NL; ++l) {
    hipMemsetAsync(red, 0, sizeof(float) * 8704, stream);
    k_qkv<<<1024, 192, 0, stream>>>(hin,
        Wq + (size_t)l * HID * 128, Wk + (size_t)l * HID * 128,
        Wv + (size_t)l * HID * 128,
        bq + (size_t)l * 128, bk + (size_t)l * 128, bv + (size_t)l * 128,
        q, kbuf, vbuf, red);
    k_kvs<<<256, 256, 0, stream>>>(kbuf, vbuf, red);
    k_combine<<<1024, 256, 0, stream>>>(q, vbuf, hin, offs, ebuf, wbuf, red,
        ln_w + (size_t)(l + 1) * HID, ln_b + (size_t)(l + 1) * HID, hot);
    float* tmp = hin; hin = hot; hot = tmp;
  }

  k_final<<<1024, 256, 0, stream>>>(hin, fco_w, fco_b, out);
}

// Round 2
// 1895.988 us; speedup vs baseline: 1.1191x; 1.1191x over previous
//
#include <hip/hip_runtime.h>
#include <math.h>

#define NNODES 100000
#define NEDGES 800000
#define DIN    256
#define HID    64
#define NC     40
#define NL     2
#define EPSL   1e-5f
#define CHUNK  1024
#define NCHUNK ((NNODES + CHUNK - 1) / CHUNK)   // 98
#define NB128  ((NNODES + 127) / 128)           // 782

__device__ __forceinline__ float wave_allsum(float v) {
#pragma unroll
  for (int off = 32; off > 0; off >>= 1) v += __shfl_xor(v, off);
  return v;
}

// ---------------- CSR build ----------------
__global__ void k_hist(const int* __restrict__ ei, int* __restrict__ deg) {
  for (int e = blockIdx.x * blockDim.x + threadIdx.x; e < NEDGES;
       e += gridDim.x * blockDim.x)
    atomicAdd(&deg[ei[NEDGES + e]], 1);
}

__global__ void k_scan1(const int* __restrict__ deg, int* __restrict__ csum) {
  __shared__ int sdata[256];
  int base = blockIdx.x * CHUNK;
  int s = 0;
  for (int t = threadIdx.x; t < CHUNK; t += 256) {
    int idx = base + t;
    if (idx < NNODES) s += deg[idx];
  }
  sdata[threadIdx.x] = s;
  __syncthreads();
  for (int off = 128; off > 0; off >>= 1) {
    if (threadIdx.x < off) sdata[threadIdx.x] += sdata[threadIdx.x + off];
    __syncthreads();
  }
  if (threadIdx.x == 0) csum[blockIdx.x] = sdata[0];
}

__global__ void k_scan2(const int* __restrict__ csum, int* __restrict__ cpref) {
  if (threadIdx.x == 0 && blockIdx.x == 0) {
    int run = 0;
    for (int i = 0; i < NCHUNK; ++i) { cpref[i] = run; run += csum[i]; }
  }
}

__global__ void k_scan3(const int* __restrict__ deg, const int* __restrict__ cpref,
                        int* __restrict__ offs) {
  __shared__ int bufA[CHUNK], bufB[CHUNK];
  int base = blockIdx.x * CHUNK;
  int orig[4];
#pragma unroll
  for (int i = 0; i < 4; ++i) {
    int t = threadIdx.x + i * 256;
    int idx = base + t;
    orig[i] = (idx < NNODES) ? deg[idx] : 0;
    bufA[t] = orig[i];
  }
  __syncthreads();
  int* src = bufA; int* dst = bufB;
  for (int off = 1; off < CHUNK; off <<= 1) {
#pragma unroll
    for (int i = 0; i < 4; ++i) {
      int t = threadIdx.x + i * 256;
      int vv = src[t];
      if (t >= off) vv += src[t - off];
      dst[t] = vv;
    }
    __syncthreads();
    int* tmp = src; src = dst; dst = tmp;
  }
  int cp = cpref[blockIdx.x];
#pragma unroll
  for (int i = 0; i < 4; ++i) {
    int t = threadIdx.x + i * 256;
    int idx = base + t;
    if (idx < NNODES) {
      offs[idx] = cp + src[t] - orig[i];
      if (idx == NNODES - 1) offs[NNODES] = cp + src[t];
    }
  }
}

__global__ void k_fill(const int* __restrict__ ei, const int* __restrict__ deg,
                       const int* __restrict__ offs, int* __restrict__ cursor,
                       int* __restrict__ ebuf, float* __restrict__ wbuf) {
  for (int e = blockIdx.x * blockDim.x + threadIdx.x; e < NEDGES;
       e += gridDim.x * blockDim.x) {
    int r = ei[e], c = ei[NEDGES + e];
    int pos = offs[c] + atomicAdd(&cursor[c], 1);
    ebuf[pos] = r;
    int dc = deg[c], dr = deg[r];
    wbuf[pos] = (dr > 0)
        ? sqrtf(1.0f / (float)dc) * sqrtf(1.0f / (float)dr) : 0.0f;
  }
}

// ---------------- fc0 + LN + relu (thread-owns-row, W via s_load) --------
__global__ __launch_bounds__(128) void k_fc0(
    const float* __restrict__ x, const float* __restrict__ w,
    const float* __restrict__ b, const float* __restrict__ lnw_,
    const float* __restrict__ lnb_, float* __restrict__ h) {
  __shared__ float xs[32 * 128];           // k-major [32][128]
  const int tid = threadIdx.x;
  const int base = blockIdx.x * 128;
  const int row = base + tid;
  const float4* x4 = (const float4*)x;
  float acc[64];
#pragma unroll
  for (int j = 0; j < 64; ++j) acc[j] = b[j];

  float4 pre[8];
#pragma unroll
  for (int i = 0; i < 8; ++i) {
    int r = i * 16 + (tid >> 3);
    int gr = base + r;
    pre[i] = (gr < NNODES) ? x4[(size_t)gr * 64 + (tid & 7)]
                           : make_float4(0.f, 0.f, 0.f, 0.f);
  }
  for (int c = 0; c < 8; ++c) {
    __syncthreads();
#pragma unroll
    for (int i = 0; i < 8; ++i) {
      int r = i * 16 + (tid >> 3);
      int kq = tid & 7;
      xs[(kq * 4 + 0) * 128 + r] = pre[i].x;
      xs[(kq * 4 + 1) * 128 + r] = pre[i].y;
      xs[(kq * 4 + 2) * 128 + r] = pre[i].z;
      xs[(kq * 4 + 3) * 128 + r] = pre[i].w;
    }
    __syncthreads();
    if (c < 7) {
#pragma unroll
      for (int i = 0; i < 8; ++i) {
        int r = i * 16 + (tid >> 3);
        int gr = base + r;
        pre[i] = (gr < NNODES) ? x4[(size_t)gr * 64 + (c + 1) * 8 + (tid & 7)]
                               : make_float4(0.f, 0.f, 0.f, 0.f);
      }
    }
    const float* wc = w + c * 32 * 64;
#pragma unroll 2
    for (int k = 0; k < 32; ++k) {
      float xv = xs[k * 128 + tid];
      const float* wr = wc + k * 64;
#pragma unroll
      for (int j = 0; j < 64; ++j) acc[j] = fmaf(xv, wr[j], acc[j]);
    }
  }
  if (row < NNODES) {
    float mu = 0.f;
#pragma unroll
    for (int j = 0; j < 64; ++j) mu += acc[j];
    mu *= (1.0f / 64.0f);
    float var = 0.f;
#pragma unroll
    for (int j = 0; j < 64; ++j) { float d = acc[j] - mu; var = fmaf(d, d, var); }
    float inv = 1.0f / sqrtf(var * (1.0f / 64.0f) + EPSL);
    float4* h4 = (float4*)(h + (size_t)row * 64);
#pragma unroll
    for (int jj = 0; jj < 16; ++jj) {
      float4 o;
      o.x = fmaxf((acc[4*jj+0] - mu) * inv * lnw_[4*jj+0] + lnb_[4*jj+0], 0.f);
      o.y = fmaxf((acc[4*jj+1] - mu) * inv * lnw_[4*jj+1] + lnb_[4*jj+1], 0.f);
      o.z = fmaxf((acc[4*jj+2] - mu) * inv * lnw_[4*jj+2] + lnb_[4*jj+2], 0.f);
      o.w = fmaxf((acc[4*jj+3] - mu) * inv * lnw_[4*jj+3] + lnb_[4*jj+3], 0.f);
      h4[jj] = o;
    }
  }
}

// ---------------- QKV GEMM (blockIdx.y selects matrix) -------------------
__global__ __launch_bounds__(128) void k_qkv(
    const float* __restrict__ h,
    const float* __restrict__ Wq, const float* __restrict__ Wk,
    const float* __restrict__ Wv,
    const float* __restrict__ bq, const float* __restrict__ bk,
    const float* __restrict__ bv,
    float* __restrict__ q, float* __restrict__ kk, float* __restrict__ vv,
    float* __restrict__ red) {
  __shared__ float hs[64 * 128];           // k-major [64][128]
  const int tid = threadIdx.x;
  const int base = blockIdx.x * 128;
  const int row = base + tid;
  const int mat = blockIdx.y;
  const float* W; const float* B; float* outp;
  if (mat == 0)      { W = Wq; B = bq; outp = q; }
  else if (mat == 1) { W = Wk; B = bk; outp = kk; }
  else               { W = Wv; B = bv; outp = vv; }

  const float4* h4 = (const float4*)h;
#pragma unroll
  for (int i = 0; i < 16; ++i) {
    int r = i * 8 + (tid >> 4);
    int kq = tid & 15;
    int gr = base + r;
    float4 t = (gr < NNODES) ? h4[(size_t)gr * 16 + kq]
                             : make_float4(0.f, 0.f, 0.f, 0.f);
    hs[(kq * 4 + 0) * 128 + r] = t.x;
    hs[(kq * 4 + 1) * 128 + r] = t.y;
    hs[(kq * 4 + 2) * 128 + r] = t.z;
    hs[(kq * 4 + 3) * 128 + r] = t.w;
  }
  __syncthreads();

  float sq = 0.f;
  for (int jc = 0; jc < 2; ++jc) {
    float acc[64];
#pragma unroll
    for (int j = 0; j < 64; ++j) acc[j] = B[jc * 64 + j];
#pragma unroll 2
    for (int k = 0; k < 64; ++k) {
      float xv = hs[k * 128 + tid];
      const float* wr = W + k * 128 + jc * 64;
#pragma unroll
      for (int j = 0; j < 64; ++j) acc[j] = fmaf(xv, wr[j], acc[j]);
    }
    if (row < NNODES) {
      float4* o4 = (float4*)(outp + (size_t)row * 128 + jc * 64);
#pragma unroll
      for (int jj = 0; jj < 16; ++jj)
        o4[jj] = make_float4(acc[4*jj], acc[4*jj+1], acc[4*jj+2], acc[4*jj+3]);
      if (mat == 0) {
#pragma unroll
        for (int j = 0; j < 64; ++j) sq = fmaf(acc[j], acc[j], sq);
      }
    }
  }
  if (mat == 0) {
    float t = wave_allsum(sq);
    if ((tid & 63) == 0) atomicAdd(&red[0], t);
  }
}

// ------- KVS + ksum + vsum + sum(k^2) + vh = 0.5*(v0+v1) ----------------
__global__ __launch_bounds__(256) void k_kvs(
    const float* __restrict__ k, const float* __restrict__ v,
    float* __restrict__ vh, float* __restrict__ red) {
  __shared__ float kc[64 * 128], vc[64 * 128];
  const int tid = threadIdx.x;
  const int hh = tid >> 7, rem = tid & 127;
  const int mm = rem >> 1, db = (rem & 1) * 32;
  float acc[32];
#pragma unroll
  for (int i = 0; i < 32; ++i) acc[i] = 0.f;
  float ksl = 0.f, vsl = 0.f, sqk = 0.f;
  const float4* k4 = (const float4*)k;
  const float4* v4 = (const float4*)v;
  for (int base = blockIdx.x * 64; base < NNODES; base += gridDim.x * 64) {
    for (int t = tid; t < 64 * 32; t += 256) {
      int node = base + (t >> 5);
      int c4 = t & 31;
      float4 kk4 = make_float4(0.f, 0.f, 0.f, 0.f), vv4 = kk4;
      if (node < NNODES) {
        kk4 = k4[(size_t)node * 32 + c4];
        vv4 = v4[(size_t)node * 32 + c4];
      }
      *(float4*)&kc[t * 4] = kk4;
      *(float4*)&vc[t * 4] = vv4;
    }
    __syncthreads();
    // column partial sums (thread -> column rem, node-half hh)
#pragma unroll 4
    for (int n = hh * 32; n < hh * 32 + 32; ++n) {
      float kv_ = kc[n * 128 + rem], vv_ = vc[n * 128 + rem];
      ksl += kv_; sqk = fmaf(kv_, kv_, sqk); vsl += vv_;
    }
    // vh = 0.5*(head0 + head1)
#pragma unroll
    for (int t = tid; t < 4096; t += 256) {
      int n = t >> 6, d = t & 63;
      if (base + n < NNODES)
        vh[(size_t)(base + n) * 64 + d] = 0.5f * (vc[n*128 + d] + vc[n*128 + 64 + d]);
    }
    // outer product accumulate
    for (int nn = 0; nn < 64; ++nn) {
      float kvv = kc[nn * 128 + hh * 64 + mm];
      const float4* vp = (const float4*)&vc[nn * 128 + hh * 64 + db];
#pragma unroll
      for (int dq = 0; dq < 8; ++dq) {
        float4 vvq = vp[dq];
        acc[4*dq+0] = fmaf(kvv, vvq.x, acc[4*dq+0]);
        acc[4*dq+1] = fmaf(kvv, vvq.y, acc[4*dq+1]);
        acc[4*dq+2] = fmaf(kvv, vvq.z, acc[4*dq+2]);
        acc[4*dq+3] = fmaf(kvv, vvq.w, acc[4*dq+3]);
      }
    }
    __syncthreads();
  }
  atomicAdd(&red[2 + rem], ksl);
  atomicAdd(&red[130 + rem], vsl);
  float t = wave_allsum(sqk);
  if ((tid & 63) == 0) atomicAdd(&red[1], t);
  float* kvs_out = red + 258 + hh * 4096 + mm * 64 + db;
#pragma unroll
  for (int dd = 0; dd < 32; ++dd) atomicAdd(&kvs_out[dd], acc[dd]);
}

// ---------------- attention numerator/denominator (thread-owns-node) -----
__global__ __launch_bounds__(128) void k_attn(
    const float* __restrict__ q, const float* __restrict__ red,
    float* __restrict__ attnm) {
  __shared__ float qs[64 * 128];
  const int tid = threadIdx.x;
  const int base = blockIdx.x * 128;
  const int row = base + tid;
  const float4* q4 = (const float4*)q;
  const float inv_qk = (1.0f / sqrtf(red[0])) * (1.0f / sqrtf(red[1]));
  float res[64];
  for (int hh = 0; hh < 2; ++hh) {
    if (hh) __syncthreads();
#pragma unroll
    for (int i = 0; i < 16; ++i) {
      int r = i * 8 + (tid >> 4);
      int kq = tid & 15;
      int gr = base + r;
      float4 t = (gr < NNODES) ? q4[(size_t)gr * 32 + hh * 16 + kq]
                               : make_float4(0.f, 0.f, 0.f, 0.f);
      qs[(kq * 4 + 0) * 128 + r] = t.x;
      qs[(kq * 4 + 1) * 128 + r] = t.y;
      qs[(kq * 4 + 2) * 128 + r] = t.z;
      qs[(kq * 4 + 3) * 128 + r] = t.w;
    }
    __syncthreads();
    float acc[64];
#pragma unroll
    for (int j = 0; j < 64; ++j) acc[j] = 0.f;
    float den = 0.f;
    const float* kvsb = red + 258 + hh * 4096;
    const float* ksb  = red + 2 + hh * 64;
#pragma unroll 2
    for (int m = 0; m < 64; ++m) {
      float qv = qs[m * 128 + tid];
      const float* kr = kvsb + m * 64;
#pragma unroll
      for (int j = 0; j < 64; ++j) acc[j] = fmaf(qv, kr[j], acc[j]);
      den = fmaf(qv, ksb[m], den);
    }
    float dd = 1.0f / (den * inv_qk + (float)NNODES);
    const float* vsb = red + 130 + hh * 64;
#pragma unroll
    for (int j = 0; j < 64; ++j) {
      float t = (acc[j] * inv_qk + vsb[j]) * dd;
      res[j] = (hh == 0) ? t : 0.5f * (res[j] + t);
    }
  }
  if (row < NNODES) {
    float4* o4 = (float4*)(attnm + (size_t)row * 64);
#pragma unroll
    for (int jj = 0; jj < 16; ++jj)
      o4[jj] = make_float4(res[4*jj], res[4*jj+1], res[4*jj+2], res[4*jj+3]);
  }
}

// ---------------- GCN gather + mean/residual + LN (wave-per-node) --------
__global__ __launch_bounds__(256) void k_gcnln(
    const float* __restrict__ attnm, const float* __restrict__ vh,
    const float* __restrict__ prev, const int* __restrict__ offs,
    const int* __restrict__ ebuf, const float* __restrict__ wbuf,
    const float* __restrict__ lnw_, const float* __restrict__ lnb_,
    float* __restrict__ hout) {
  const int wave = threadIdx.x >> 6, lane = threadIdx.x & 63;
  const float lw = lnw_[lane], lb = lnb_[lane];
  for (int node = blockIdx.x * 4 + wave; node < NNODES; node += gridDim.x * 4) {
    float g = 0.f;
    int s = offs[node], e = offs[node + 1];
    int i = s;
    for (; i + 1 < e; i += 2) {
      int s0 = ebuf[i], s1 = ebuf[i + 1];
      float w0 = wbuf[i], w1 = wbuf[i + 1];
      float v0 = vh[(size_t)s0 * 64 + lane];
      float v1 = vh[(size_t)s1 * 64 + lane];
      g = fmaf(w0, v0, g);
      g = fmaf(w1, v1, g);
    }
    if (i < e) g = fmaf(wbuf[i], vh[(size_t)ebuf[i] * 64 + lane], g);
    float om = attnm[(size_t)node * 64 + lane] + g;
    float pre = 0.5f * om + 0.5f * prev[(size_t)node * 64 + lane];
    float mu = wave_allsum(pre) * (1.0f / 64.0f);
    float d = pre - mu;
    float var = wave_allsum(d * d) * (1.0f / 64.0f);
    hout[(size_t)node * 64 + lane] = d * (1.0f / sqrtf(var + EPSL)) * lw + lb;
  }
}

// ---------------- final classifier (thread-owns-row) ---------------------
__global__ __launch_bounds__(128) void k_final(
    const float* __restrict__ h, const float* __restrict__ w,
    const float* __restrict__ b, float* __restrict__ out) {
  __shared__ float hs[64 * 128];
  const int tid = threadIdx.x;
  const int base = blockIdx.x * 128;
  const int row = base + tid;
  const float4* h4 = (const float4*)h;
#pragma unroll
  for (int i = 0; i < 16; ++i) {
    int r = i * 8 + (tid >> 4);
    int kq = tid & 15;
    int gr = base + r;
    float4 t = (gr < NNODES) ? h4[(size_t)gr * 16 + kq]
                             : make_float4(0.f, 0.f, 0.f, 0.f);
    hs[(kq * 4 + 0) * 128 + r] = t.x;
    hs[(kq * 4 + 1) * 128 + r] = t.y;
    hs[(kq * 4 + 2) * 128 + r] = t.z;
    hs[(kq * 4 + 3) * 128 + r] = t.w;
  }
  __syncthreads();
  float acc[NC];
#pragma unroll
  for (int j = 0; j < NC; ++j) acc[j] = b[j];
#pragma unroll 2
  for (int k = 0; k < 64; ++k) {
    float xv = hs[k * 128 + tid];
    const float* wr = w + k * NC;
#pragma unroll
    for (int j = 0; j < NC; ++j) acc[j] = fmaf(xv, wr[j], acc[j]);
  }
  if (row < NNODES) {
    float4* o4 = (float4*)(out + (size_t)row * NC);
#pragma unroll
    for (int jj = 0; jj < NC / 4; ++jj)
      o4[jj] = make_float4(acc[4*jj], acc[4*jj+1], acc[4*jj+2], acc[4*jj+3]);
  }
}

extern "C" void kernel_launch(void* const* d_in, const int* in_sizes, int n_in,
                              void* d_out, int out_size, void* d_ws,
                              size_t ws_size, hipStream_t stream) {
  const float* x     = (const float*)d_in[0];
  const int*   ei    = (const int*)d_in[1];
  const float* fc0_w = (const float*)d_in[2];
  const float* fc0_b = (const float*)d_in[3];
  const float* ln_w  = (const float*)d_in[4];
  const float* ln_b  = (const float*)d_in[5];
  const float* Wq    = (const float*)d_in[6];
  const float* Wk    = (const float*)d_in[7];
  const float* Wv    = (const float*)d_in[8];
  const float* bq    = (const float*)d_in[9];
  const float* bk    = (const float*)d_in[10];
  const float* bv    = (const float*)d_in[11];
  const float* fco_w = (const float*)d_in[12];
  const float* fco_b = (const float*)d_in[13];
  float* out = (float*)d_out;

  char* p = (char*)d_ws;
  auto alloc = [&](size_t bytes) {
    char* r = p;
    p += (bytes + 255) & ~(size_t)255;
    return r;
  };
  float* q    = (float*)alloc(sizeof(float) * (size_t)NNODES * 128);
  float* kbuf = (float*)alloc(sizeof(float) * (size_t)NNODES * 128);
  float* vbuf = (float*)alloc(sizeof(float) * (size_t)NNODES * 128);
  float* hA   = (float*)alloc(sizeof(float) * (size_t)NNODES * HID);
  float* hB   = (float*)alloc(sizeof(float) * (size_t)NNODES * HID);
  float* vh   = (float*)alloc(sizeof(float) * (size_t)NNODES * HID);
  float* red  = (float*)alloc(sizeof(float) * 8704);
  int* deg    = (int*)alloc(sizeof(int) * NNODES);
  int* offs   = (int*)alloc(sizeof(int) * (NNODES + 1));
  int* cursor = (int*)alloc(sizeof(int) * NNODES);
  int* ebuf   = (int*)alloc(sizeof(int) * NEDGES);
  float* wbuf = (float*)alloc(sizeof(float) * NEDGES);
  int* csum   = (int*)alloc(sizeof(int) * 128);
  int* cpref  = (int*)alloc(sizeof(int) * 128);
  float* attnm = kbuf;   // kbuf dead after k_kvs; reuse as attnm

  // ---- CSR build ----
  hipMemsetAsync(deg, 0, sizeof(int) * NNODES, stream);
  hipMemsetAsync(cursor, 0, sizeof(int) * NNODES, stream);
  k_hist<<<1024, 256, 0, stream>>>(ei, deg);
  k_scan1<<<NCHUNK, 256, 0, stream>>>(deg, csum);
  k_scan2<<<1, 64, 0, stream>>>(csum, cpref);
  k_scan3<<<NCHUNK, 256, 0, stream>>>(deg, cpref, offs);
  k_fill<<<1024, 256, 0, stream>>>(ei, deg, offs, cursor, ebuf, wbuf);

  // ---- input projection ----
  k_fc0<<<NB128, 128, 0, stream>>>(x, fc0_w, fc0_b, ln_w, ln_b, hA);

  float* hin = hA;
  float* hot = hB;
  for (int l = 0; l < NL; ++l) {
    hipMemsetAsync(red, 0, sizeof(float) * 8704, stream);
    k_qkv<<<dim3(NB128, 3), 128, 0, stream>>>(hin,
        Wq + (size_t)l * HID * 128, Wk + (size_t)l * HID * 128,
        Wv + (size_t)l * HID * 128,
        bq + (size_t)l * 128, bk + (size_t)l * 128, bv + (size_t)l * 128,
        q, kbuf, vbuf, red);
    k_kvs<<<512, 256, 0, stream>>>(kbuf, vbuf, vh, red);
    k_attn<<<NB128, 128, 0, stream>>>(q, red, attnm);
    k_gcnln<<<2048, 256, 0, stream>>>(attnm, vh, hin, offs, ebuf, wbuf,
        ln_w + (size_t)(l + 1) * HID, ln_b + (size_t)(l + 1) * HID, hot);
    float* tmp = hin; hin = hot; hot = tmp;
  }

  k_final<<<NB128, 128, 0, stream>>>(hin, fco_w, fco_b, out);
}

// Round 4
// 1164.855 us; speedup vs baseline: 1.8215x; 1.6277x over previous
//
#include <hip/hip_runtime.h>
#include <math.h>

#define NNODES 100000
#define NEDGES 800000
#define DIN    256
#define HID    64
#define NC     40
#define NL     2
#define EPSL   1e-5f
#define CHUNK  1024
#define NCHUNK ((NNODES + CHUNK - 1) / CHUNK)   // 98
#define NB128  ((NNODES + 127) / 128)           // 782
#define NKVB   512                              // kvs partial blocks
#define SLAB   8720                             // floats per block slab

__device__ __forceinline__ float wave_allsum(float v) {
#pragma unroll
  for (int off = 32; off > 0; off >>= 1) v += __shfl_xor(v, off);
  return v;
}

// ---------------- CSR build ----------------
__global__ void k_hist(const int* __restrict__ ei, int* __restrict__ deg) {
  for (int e = blockIdx.x * blockDim.x + threadIdx.x; e < NEDGES;
       e += gridDim.x * blockDim.x)
    atomicAdd(&deg[ei[NEDGES + e]], 1);
}

__global__ void k_scan1(const int* __restrict__ deg, int* __restrict__ csum) {
  __shared__ int sdata[256];
  int base = blockIdx.x * CHUNK;
  int s = 0;
  for (int t = threadIdx.x; t < CHUNK; t += 256) {
    int idx = base + t;
    if (idx < NNODES) s += deg[idx];
  }
  sdata[threadIdx.x] = s;
  __syncthreads();
  for (int off = 128; off > 0; off >>= 1) {
    if (threadIdx.x < off) sdata[threadIdx.x] += sdata[threadIdx.x + off];
    __syncthreads();
  }
  if (threadIdx.x == 0) csum[blockIdx.x] = sdata[0];
}

__global__ void k_scan2(const int* __restrict__ csum, int* __restrict__ cpref) {
  if (threadIdx.x == 0 && blockIdx.x == 0) {
    int run = 0;
    for (int i = 0; i < NCHUNK; ++i) { cpref[i] = run; run += csum[i]; }
  }
}

__global__ void k_scan3(const int* __restrict__ deg, const int* __restrict__ cpref,
                        int* __restrict__ offs) {
  __shared__ int bufA[CHUNK], bufB[CHUNK];
  int base = blockIdx.x * CHUNK;
  int orig[4];
#pragma unroll
  for (int i = 0; i < 4; ++i) {
    int t = threadIdx.x + i * 256;
    int idx = base + t;
    orig[i] = (idx < NNODES) ? deg[idx] : 0;
    bufA[t] = orig[i];
  }
  __syncthreads();
  int* src = bufA; int* dst = bufB;
  for (int off = 1; off < CHUNK; off <<= 1) {
#pragma unroll
    for (int i = 0; i < 4; ++i) {
      int t = threadIdx.x + i * 256;
      int vv = src[t];
      if (t >= off) vv += src[t - off];
      dst[t] = vv;
    }
    __syncthreads();
    int* tmp = src; src = dst; dst = tmp;
  }
  int cp = cpref[blockIdx.x];
#pragma unroll
  for (int i = 0; i < 4; ++i) {
    int t = threadIdx.x + i * 256;
    int idx = base + t;
    if (idx < NNODES) {
      offs[idx] = cp + src[t] - orig[i];
      if (idx == NNODES - 1) offs[NNODES] = cp + src[t];
    }
  }
}

__global__ void k_fill(const int* __restrict__ ei, const int* __restrict__ deg,
                       const int* __restrict__ offs, int* __restrict__ cursor,
                       int2* __restrict__ epack) {
  for (int e = blockIdx.x * blockDim.x + threadIdx.x; e < NEDGES;
       e += gridDim.x * blockDim.x) {
    int r = ei[e], c = ei[NEDGES + e];
    int pos = offs[c] + atomicAdd(&cursor[c], 1);
    int dc = deg[c], dr = deg[r];
    float w = (dr > 0)
        ? sqrtf(1.0f / (float)dc) * sqrtf(1.0f / (float)dr) : 0.0f;
    epack[pos] = make_int2(r, __float_as_int(w));
  }
}

// ---------------- fc0 + LN + relu (thread-owns-row, W via s_load) --------
__global__ __launch_bounds__(128) void k_fc0(
    const float* __restrict__ x, const float* __restrict__ w,
    const float* __restrict__ b, const float* __restrict__ lnw_,
    const float* __restrict__ lnb_, float* __restrict__ h) {
  __shared__ float xs[32 * 128];           // k-major [32][128]
  const int tid = threadIdx.x;
  const int base = blockIdx.x * 128;
  const int row = base + tid;
  const float4* x4 = (const float4*)x;
  float acc[64];
#pragma unroll
  for (int j = 0; j < 64; ++j) acc[j] = b[j];

  float4 pre[8];
#pragma unroll
  for (int i = 0; i < 8; ++i) {
    int r = i * 16 + (tid >> 3);
    int gr = base + r;
    pre[i] = (gr < NNODES) ? x4[(size_t)gr * 64 + (tid & 7)]
                           : make_float4(0.f, 0.f, 0.f, 0.f);
  }
  for (int c = 0; c < 8; ++c) {
    __syncthreads();
#pragma unroll
    for (int i = 0; i < 8; ++i) {
      int r = i * 16 + (tid >> 3);
      int kq = tid & 7;
      xs[(kq * 4 + 0) * 128 + r] = pre[i].x;
      xs[(kq * 4 + 1) * 128 + r] = pre[i].y;
      xs[(kq * 4 + 2) * 128 + r] = pre[i].z;
      xs[(kq * 4 + 3) * 128 + r] = pre[i].w;
    }
    __syncthreads();
    if (c < 7) {
#pragma unroll
      for (int i = 0; i < 8; ++i) {
        int r = i * 16 + (tid >> 3);
        int gr = base + r;
        pre[i] = (gr < NNODES) ? x4[(size_t)gr * 64 + (c + 1) * 8 + (tid & 7)]
                               : make_float4(0.f, 0.f, 0.f, 0.f);
      }
    }
    const float* wc = w + c * 32 * 64;
#pragma unroll 2
    for (int k = 0; k < 32; ++k) {
      float xv = xs[k * 128 + tid];
      const float* wr = wc + k * 64;
#pragma unroll
      for (int j = 0; j < 64; ++j) acc[j] = fmaf(xv, wr[j], acc[j]);
    }
  }
  if (row < NNODES) {
    float mu = 0.f;
#pragma unroll
    for (int j = 0; j < 64; ++j) mu += acc[j];
    mu *= (1.0f / 64.0f);
    float var = 0.f;
#pragma unroll
    for (int j = 0; j < 64; ++j) { float d = acc[j] - mu; var = fmaf(d, d, var); }
    float inv = 1.0f / sqrtf(var * (1.0f / 64.0f) + EPSL);
    float4* h4 = (float4*)(h + (size_t)row * 64);
#pragma unroll
    for (int jj = 0; jj < 16; ++jj) {
      float4 o;
      o.x = fmaxf((acc[4*jj+0] - mu) * inv * lnw_[4*jj+0] + lnb_[4*jj+0], 0.f);
      o.y = fmaxf((acc[4*jj+1] - mu) * inv * lnw_[4*jj+1] + lnb_[4*jj+1], 0.f);
      o.z = fmaxf((acc[4*jj+2] - mu) * inv * lnw_[4*jj+2] + lnb_[4*jj+2], 0.f);
      o.w = fmaxf((acc[4*jj+3] - mu) * inv * lnw_[4*jj+3] + lnb_[4*jj+3], 0.f);
      h4[jj] = o;
    }
  }
}

// ---------------- QKV GEMM (blockIdx.y selects matrix) -------------------
__global__ __launch_bounds__(128) void k_qkv(
    const float* __restrict__ h,
    const float* __restrict__ Wq, const float* __restrict__ Wk,
    const float* __restrict__ Wv,
    const float* __restrict__ bq, const float* __restrict__ bk,
    const float* __restrict__ bv,
    float* __restrict__ q, float* __restrict__ kk, float* __restrict__ vv,
    float* __restrict__ red) {
  __shared__ float hs[64 * 128];           // k-major [64][128]
  const int tid = threadIdx.x;
  const int base = blockIdx.x * 128;
  const int row = base + tid;
  const int mat = blockIdx.y;
  const float* W; const float* B; float* outp;
  if (mat == 0)      { W = Wq; B = bq; outp = q; }
  else if (mat == 1) { W = Wk; B = bk; outp = kk; }
  else               { W = Wv; B = bv; outp = vv; }

  const float4* h4 = (const float4*)h;
#pragma unroll
  for (int i = 0; i < 16; ++i) {
    int r = i * 8 + (tid >> 4);
    int kq = tid & 15;
    int gr = base + r;
    float4 t = (gr < NNODES) ? h4[(size_t)gr * 16 + kq]
                             : make_float4(0.f, 0.f, 0.f, 0.f);
    hs[(kq * 4 + 0) * 128 + r] = t.x;
    hs[(kq * 4 + 1) * 128 + r] = t.y;
    hs[(kq * 4 + 2) * 128 + r] = t.z;
    hs[(kq * 4 + 3) * 128 + r] = t.w;
  }
  __syncthreads();

  float sq = 0.f;
  for (int jc = 0; jc < 2; ++jc) {
    float acc[64];
#pragma unroll
    for (int j = 0; j < 64; ++j) acc[j] = B[jc * 64 + j];
#pragma unroll 2
    for (int k = 0; k < 64; ++k) {
      float xv = hs[k * 128 + tid];
      const float* wr = W + k * 128 + jc * 64;
#pragma unroll
      for (int j = 0; j < 64; ++j) acc[j] = fmaf(xv, wr[j], acc[j]);
    }
    if (row < NNODES) {
      float4* o4 = (float4*)(outp + (size_t)row * 128 + jc * 64);
#pragma unroll
      for (int jj = 0; jj < 16; ++jj)
        o4[jj] = make_float4(acc[4*jj], acc[4*jj+1], acc[4*jj+2], acc[4*jj+3]);
      if (mat == 0) {
#pragma unroll
        for (int j = 0; j < 64; ++j) sq = fmaf(acc[j], acc[j], sq);
      }
    }
  }
  if (mat == 0) {
    float t = wave_allsum(sq);
    if ((tid & 63) == 0) atomicAdd(&red[0], t);
  }
}

// ------- KVS partials (no atomics) + ksum/vsum/sum(k^2) + vh -------------
// slab layout per block: [0,8192) KVS  [8192,8448) ksum(per-tid)
//                        [8448,8704) vsum(per-tid)  [8704] sum k^2
__global__ __launch_bounds__(256) void k_kvs(
    const float* __restrict__ k, const float* __restrict__ v,
    float* __restrict__ vh, float* __restrict__ slab) {
  __shared__ float kc[64 * 128], vc[64 * 128];
  __shared__ float sred[4];
  const int tid = threadIdx.x;
  const int hh = tid >> 7;        // head
  const int t2 = tid & 127;
  const int mt = t2 >> 3;         // 0..15 -> m-tile of 4
  const int dt = t2 & 7;          // 0..7  -> d-tile of 8
  float acc[4][8];
#pragma unroll
  for (int a = 0; a < 4; ++a)
#pragma unroll
    for (int bq_ = 0; bq_ < 8; ++bq_) acc[a][bq_] = 0.f;
  float ksl = 0.f, vsl = 0.f, sqk = 0.f;
  const float4* k4 = (const float4*)k;
  const float4* v4 = (const float4*)v;

  for (int base = blockIdx.x * 64; base < NNODES; base += NKVB * 64) {
    if (base + 64 <= NNODES) {
      for (int t = tid; t < 2048; t += 256) {
        *(float4*)&kc[t * 4] = k4[(size_t)base * 32 + t];
        *(float4*)&vc[t * 4] = v4[(size_t)base * 32 + t];
      }
    } else {
      for (int t = tid; t < 2048; t += 256) {
        int node = base + (t >> 5);
        int c4 = t & 31;
        float4 kk4 = make_float4(0.f, 0.f, 0.f, 0.f), vv4 = kk4;
        if (node < NNODES) {
          kk4 = k4[(size_t)node * 32 + c4];
          vv4 = v4[(size_t)node * 32 + c4];
        }
        *(float4*)&kc[t * 4] = kk4;
        *(float4*)&vc[t * 4] = vv4;
      }
    }
    __syncthreads();
    // column partial sums: thread -> column t2, node-half hh
#pragma unroll 4
    for (int n = hh * 32; n < hh * 32 + 32; ++n) {
      float kv_ = kc[n * 128 + t2], vv_ = vc[n * 128 + t2];
      ksl += kv_; sqk = fmaf(kv_, kv_, sqk); vsl += vv_;
    }
    // vh = 0.5*(head0 + head1)
    for (int t = tid; t < 4096; t += 256) {
      int n = t >> 6, d = t & 63;
      if (base + n < NNODES)
        vh[(size_t)(base + n) * 64 + d] =
            0.5f * (vc[n * 128 + d] + vc[n * 128 + 64 + d]);
    }
    // outer product: 4m x 8d register tile per thread
#pragma unroll 8
    for (int nn = 0; nn < 64; ++nn) {
      const float4 kk = *(const float4*)&kc[nn * 128 + hh * 64 + mt * 4];
      const float4 va = *(const float4*)&vc[nn * 128 + hh * 64 + dt * 8];
      const float4 vb = *(const float4*)&vc[nn * 128 + hh * 64 + dt * 8 + 4];
#pragma unroll
      for (int a = 0; a < 4; ++a) {
        float kx = (a == 0) ? kk.x : (a == 1) ? kk.y : (a == 2) ? kk.z : kk.w;
        acc[a][0] = fmaf(kx, va.x, acc[a][0]);
        acc[a][1] = fmaf(kx, va.y, acc[a][1]);
        acc[a][2] = fmaf(kx, va.z, acc[a][2]);
        acc[a][3] = fmaf(kx, va.w, acc[a][3]);
        acc[a][4] = fmaf(kx, vb.x, acc[a][4]);
        acc[a][5] = fmaf(kx, vb.y, acc[a][5]);
        acc[a][6] = fmaf(kx, vb.z, acc[a][6]);
        acc[a][7] = fmaf(kx, vb.w, acc[a][7]);
      }
    }
    __syncthreads();
  }
  float* sb = slab + (size_t)blockIdx.x * SLAB;
#pragma unroll
  for (int a = 0; a < 4; ++a) {
    *(float4*)&sb[hh * 4096 + (mt * 4 + a) * 64 + dt * 8] =
        make_float4(acc[a][0], acc[a][1], acc[a][2], acc[a][3]);
    *(float4*)&sb[hh * 4096 + (mt * 4 + a) * 64 + dt * 8 + 4] =
        make_float4(acc[a][4], acc[a][5], acc[a][6], acc[a][7]);
  }
  sb[8192 + tid] = ksl;
  sb[8448 + tid] = vsl;
  float ws = wave_allsum(sqk);
  if ((tid & 63) == 0) sred[tid >> 6] = ws;
  __syncthreads();
  if (tid == 0) sb[8704] = sred[0] + sred[1] + sred[2] + sred[3];
}

// ---------------- reduce slabs -> red ------------------------------------
__global__ __launch_bounds__(256) void k_red(
    const float* __restrict__ slab, float* __restrict__ red) {
  int idx = blockIdx.x * 256 + threadIdx.x;
  if (idx < 8192) {
    float s = 0.f;
#pragma unroll 4
    for (int b = 0; b < NKVB; ++b) s += slab[(size_t)b * SLAB + idx];
    red[258 + idx] = s;
  } else if (idx < 8320) {
    int r = idx - 8192;
    float s = 0.f;
#pragma unroll 4
    for (int b = 0; b < NKVB; ++b)
      s += slab[(size_t)b * SLAB + 8192 + r] +
           slab[(size_t)b * SLAB + 8192 + 128 + r];
    red[2 + r] = s;
  } else if (idx < 8448) {
    int r = idx - 8320;
    float s = 0.f;
#pragma unroll 4
    for (int b = 0; b < NKVB; ++b)
      s += slab[(size_t)b * SLAB + 8448 + r] +
           slab[(size_t)b * SLAB + 8448 + 128 + r];
    red[130 + r] = s;
  } else if (idx == 8448) {
    float s = 0.f;
#pragma unroll 4
    for (int b = 0; b < NKVB; ++b) s += slab[(size_t)b * SLAB + 8704];
    red[1] = s;
  }
}

// ---------------- attention numerator/denominator (thread-owns-node) -----
__global__ __launch_bounds__(128) void k_attn(
    const float* __restrict__ q, const float* __restrict__ red,
    float* __restrict__ attnm) {
  __shared__ float qs[64 * 128];
  const int tid = threadIdx.x;
  const int base = blockIdx.x * 128;
  const int row = base + tid;
  const float4* q4 = (const float4*)q;
  const float inv_qk = (1.0f / sqrtf(red[0])) * (1.0f / sqrtf(red[1]));
  float res[64];
  for (int hh = 0; hh < 2; ++hh) {
    if (hh) __syncthreads();
#pragma unroll
    for (int i = 0; i < 16; ++i) {
      int r = i * 8 + (tid >> 4);
      int kq = tid & 15;
      int gr = base + r;
      float4 t = (gr < NNODES) ? q4[(size_t)gr * 32 + hh * 16 + kq]
                               : make_float4(0.f, 0.f, 0.f, 0.f);
      qs[(kq * 4 + 0) * 128 + r] = t.x;
      qs[(kq * 4 + 1) * 128 + r] = t.y;
      qs[(kq * 4 + 2) * 128 + r] = t.z;
      qs[(kq * 4 + 3) * 128 + r] = t.w;
    }
    __syncthreads();
    float acc[64];
#pragma unroll
    for (int j = 0; j < 64; ++j) acc[j] = 0.f;
    float den = 0.f;
    const float* kvsb = red + 258 + hh * 4096;
    const float* ksb  = red + 2 + hh * 64;
#pragma unroll 2
    for (int m = 0; m < 64; ++m) {
      float qv = qs[m * 128 + tid];
      const float* kr = kvsb + m * 64;
#pragma unroll
      for (int j = 0; j < 64; ++j) acc[j] = fmaf(qv, kr[j], acc[j]);
      den = fmaf(qv, ksb[m], den);
    }
    float dd = 1.0f / (den * inv_qk + (float)NNODES);
    const float* vsb = red + 130 + hh * 64;
#pragma unroll
    for (int j = 0; j < 64; ++j) {
      float t = (acc[j] * inv_qk + vsb[j]) * dd;
      res[j] = (hh == 0) ? t : 0.5f * (res[j] + t);
    }
  }
  if (row < NNODES) {
    float4* o4 = (float4*)(attnm + (size_t)row * 64);
#pragma unroll
    for (int jj = 0; jj < 16; ++jj)
      o4[jj] = make_float4(res[4*jj], res[4*jj+1], res[4*jj+2], res[4*jj+3]);
  }
}

// ---------------- GCN gather + mean/residual + LN (wave-per-node) --------
__global__ __launch_bounds__(256) void k_gcnln(
    const float* __restrict__ attnm, const float* __restrict__ vh,
    const float* __restrict__ prev, const int* __restrict__ offs,
    const int2* __restrict__ epack,
    const float* __restrict__ lnw_, const float* __restrict__ lnb_,
    float* __restrict__ hout) {
  const int wave = threadIdx.x >> 6, lane = threadIdx.x & 63;
  const float lw = lnw_[lane], lb = lnb_[lane];
  for (int node = blockIdx.x * 4 + wave; node < NNODES; node += gridDim.x * 4) {
    float g = 0.f;
    int s = offs[node], e = offs[node + 1];
    int i = s;
    for (; i + 1 < e; i += 2) {
      int2 e0 = epack[i], e1 = epack[i + 1];
      float v0 = vh[(size_t)e0.x * 64 + lane];
      float v1 = vh[(size_t)e1.x * 64 + lane];
      g = fmaf(__int_as_float(e0.y), v0, g);
      g = fmaf(__int_as_float(e1.y), v1, g);
    }
    if (i < e) {
      int2 e0 = epack[i];
      g = fmaf(__int_as_float(e0.y), vh[(size_t)e0.x * 64 + lane], g);
    }
    float om = attnm[(size_t)node * 64 + lane] + g;
    float pre = 0.5f * om + 0.5f * prev[(size_t)node * 64 + lane];
    float mu = wave_allsum(pre) * (1.0f / 64.0f);
    float d = pre - mu;
    float var = wave_allsum(d * d) * (1.0f / 64.0f);
    hout[(size_t)node * 64 + lane] = d * (1.0f / sqrtf(var + EPSL)) * lw + lb;
  }
}

// ---------------- final classifier (thread-owns-row) ---------------------
__global__ __launch_bounds__(128) void k_final(
    const float* __restrict__ h, const float* __restrict__ w,
    const float* __restrict__ b, float* __restrict__ out) {
  __shared__ float hs[64 * 128];
  const int tid = threadIdx.x;
  const int base = blockIdx.x * 128;
  const int row = base + tid;
  const float4* h4 = (const float4*)h;
#pragma unroll
  for (int i = 0; i < 16; ++i) {
    int r = i * 8 + (tid >> 4);
    int kq = tid & 15;
    int gr = base + r;
    float4 t = (gr < NNODES) ? h4[(size_t)gr * 16 + kq]
                             : make_float4(0.f, 0.f, 0.f, 0.f);
    hs[(kq * 4 + 0) * 128 + r] = t.x;
    hs[(kq * 4 + 1) * 128 + r] = t.y;
    hs[(kq * 4 + 2) * 128 + r] = t.z;
    hs[(kq * 4 + 3) * 128 + r] = t.w;
  }
  __syncthreads();
  float acc[NC];
#pragma unroll
  for (int j = 0; j < NC; ++j) acc[j] = b[j];
#pragma unroll 2
  for (int k = 0; k < 64; ++k) {
    float xv = hs[k * 128 + tid];
    const float* wr = w + k * NC;
#pragma unroll
    for (int j = 0; j < NC; ++j) acc[j] = fmaf(xv, wr[j], acc[j]);
  }
  if (row < NNODES) {
    float4* o4 = (float4*)(out + (size_t)row * NC);
#pragma unroll
    for (int jj = 0; jj < NC / 4; ++jj)
      o4[jj] = make_float4(acc[4*jj], acc[4*jj+1], acc[4*jj+2], acc[4*jj+3]);
  }
}

extern "C" void kernel_launch(void* const* d_in, const int* in_sizes, int n_in,
                              void* d_out, int out_size, void* d_ws,
                              size_t ws_size, hipStream_t stream) {
  const float* x     = (const float*)d_in[0];
  const int*   ei    = (const int*)d_in[1];
  const float* fc0_w = (const float*)d_in[2];
  const float* fc0_b = (const float*)d_in[3];
  const float* ln_w  = (const float*)d_in[4];
  const float* ln_b  = (const float*)d_in[5];
  const float* Wq    = (const float*)d_in[6];
  const float* Wk    = (const float*)d_in[7];
  const float* Wv    = (const float*)d_in[8];
  const float* bq    = (const float*)d_in[9];
  const float* bk    = (const float*)d_in[10];
  const float* bv    = (const float*)d_in[11];
  const float* fco_w = (const float*)d_in[12];
  const float* fco_b = (const float*)d_in[13];
  float* out = (float*)d_out;

  char* p = (char*)d_ws;
  auto alloc = [&](size_t bytes) {
    char* r = p;
    p += (bytes + 255) & ~(size_t)255;
    return r;
  };
  float* q    = (float*)alloc(sizeof(float) * (size_t)NNODES * 128);
  float* kbuf = (float*)alloc(sizeof(float) * (size_t)NNODES * 128);
  float* vbuf = (float*)alloc(sizeof(float) * (size_t)NNODES * 128);
  float* hA   = (float*)alloc(sizeof(float) * (size_t)NNODES * HID);
  float* hB   = (float*)alloc(sizeof(float) * (size_t)NNODES * HID);
  float* vh   = (float*)alloc(sizeof(float) * (size_t)NNODES * HID);
  float* red  = (float*)alloc(sizeof(float) * 8704);
  float* slab = (float*)alloc(sizeof(float) * (size_t)NKVB * SLAB);
  int* deg    = (int*)alloc(sizeof(int) * NNODES);
  int* offs   = (int*)alloc(sizeof(int) * (NNODES + 1));
  int* cursor = (int*)alloc(sizeof(int) * NNODES);
  int2* epack = (int2*)alloc(sizeof(int2) * NEDGES);
  int* csum   = (int*)alloc(sizeof(int) * 128);
  int* cpref  = (int*)alloc(sizeof(int) * 128);
  float* attnm = kbuf;   // kbuf dead after k_kvs; reuse as attnm

  // ---- CSR build ----
  hipMemsetAsync(deg, 0, sizeof(int) * NNODES, stream);
  hipMemsetAsync(cursor, 0, sizeof(int) * NNODES, stream);
  k_hist<<<1024, 256, 0, stream>>>(ei, deg);
  k_scan1<<<NCHUNK, 256, 0, stream>>>(deg, csum);
  k_scan2<<<1, 64, 0, stream>>>(csum, cpref);
  k_scan3<<<NCHUNK, 256, 0, stream>>>(deg, cpref, offs);
  k_fill<<<1024, 256, 0, stream>>>(ei, deg, offs, cursor, epack);

  // ---- input projection ----
  k_fc0<<<NB128, 128, 0, stream>>>(x, fc0_w, fc0_b, ln_w, ln_b, hA);

  float* hin = hA;
  float* hot = hB;
  for (int l = 0; l < NL; ++l) {
    hipMemsetAsync(red, 0, sizeof(float) * 2, stream);
    k_qkv<<<dim3(NB128, 3), 128, 0, stream>>>(hin,
        Wq + (size_t)l * HID * 128, Wk + (size_t)l * HID * 128,
        Wv + (size_t)l * HID * 128,
        bq + (size_t)l * 128, bk + (size_t)l * 128, bv + (size_t)l * 128,
        q, kbuf, vbuf, red);
    k_kvs<<<NKVB, 256, 0, stream>>>(kbuf, vbuf, vh, slab);
    k_red<<<34, 256, 0, stream>>>(slab, red);
    k_attn<<<NB128, 128, 0, stream>>>(q, red, attnm);
    k_gcnln<<<2048, 256, 0, stream>>>(attnm, vh, hin, offs, epack,
        ln_w + (size_t)(l + 1) * HID, ln_b + (size_t)(l + 1) * HID, hot);
    float* tmp = hin; hin = hot; hot = tmp;
  }

  k_final<<<NB128, 128, 0, stream>>>(hin, fco_w, fco_b, out);
}